// Round 10
// baseline (314.543 us; speedup 1.0000x reference)
//
#include <hip/hip_runtime.h>
#include <math.h>

typedef _Float16 f16x8 __attribute__((ext_vector_type(8)));
typedef _Float16 f16x4 __attribute__((ext_vector_type(4)));
typedef float f32x16 __attribute__((ext_vector_type(16)));

__device__ __forceinline__ void async_copy16(const void* g, void* l) {
    __builtin_amdgcn_global_load_lds(
        (const __attribute__((address_space(1))) void*)g,
        (__attribute__((address_space(3))) void*)l, 16, 0, 0);
}

// ---------------- fused prep, 32KB LDS (5 blk/CU): cast | W0 halves | W1 halves ----------------
// blocks 0..1023    : cast x->f16 (8 float4/thread)  [LDS unused]
// blocks 1024..1535 : W0t build, (o,p,qh) = idx{>>5, (>>1)&15, &1}; q-range qh*8..+8
// blocks 1536..1791 : W1t build, (o,p,qh) = idx{>>5, (>>1)&15, &1}; q-range qh*4..+4
// G shrunk to 8192 floats (32KB) via the qh split -> whole kernel 5 blk/CU
// (R9 theory: shared 64KB G capped ALL 1792 blocks incl. cast at 2 blk/CU).
__global__ __launch_bounds__(256) void prep_kernel(
    const float* __restrict__ x, _Float16* __restrict__ xh,
    const float* __restrict__ c0a, const float* __restrict__ c0b,
    const float* __restrict__ c0c, _Float16* __restrict__ W0t,
    const float* __restrict__ c1a, const float* __restrict__ c1b,
    const float* __restrict__ c1c, _Float16* __restrict__ W1t) {
    __shared__ float G[8192];
    const int b = blockIdx.x, t = threadIdx.x;
    if (b < 1024) {
        const float4* in4 = (const float4*)x;
        f16x4* out4 = (f16x4*)xh;
        const int base = b * 2048 + t;
#pragma unroll
        for (int u = 0; u < 8; ++u) {
            float4 v = in4[base + u * 256];
            f16x4 o;
            o[0] = (_Float16)v.x; o[1] = (_Float16)v.y;
            o[2] = (_Float16)v.z; o[3] = (_Float16)v.w;
            out4[base + u * 256] = o;
        }
    } else if (b < 1536) {
        const int idx = b - 1024;
        const int o = idx >> 5, p = (idx >> 1) & 15, qh = idx & 1;
        // phase1: G[ql8][rj128][k8] = sum_ss c0b[rj,p,ss]*c0c[ss,k,q], q=qh*8+ql
        {
            const int h = t >> 6, pair = t & 63, ql = pair >> 3, k = pair & 7;
            const int q = qh * 8 + ql;
            float cr[8];
#pragma unroll
            for (int ss = 0; ss < 8; ++ss) cr[ss] = c0c[(ss * 8 + k) * 16 + q];
            for (int rj = h * 32; rj < h * 32 + 32; ++rj) {
                const float4* b4 = (const float4*)(c0b + (rj * 16 + p) * 8);
                float4 b0 = b4[0], b1 = b4[1];
                float s = b0.x * cr[0] + b0.y * cr[1] + b0.z * cr[2] + b0.w * cr[3]
                        + b1.x * cr[4] + b1.y * cr[5] + b1.z * cr[6] + b1.w * cr[7];
                G[ql * 1024 + rj * 8 + k] = s;
            }
        }
        __syncthreads();
        // phase2: W0t row (o*16+p)*16+q, q = qh*8+ql
        const int i = t >> 5, j = (t >> 1) & 15, kq = t & 1;
        float a[8];
#pragma unroll
        for (int r = 0; r < 8; ++r) a[r] = c0a[(i * 16 + o) * 8 + r];
        const float4* G4 = (const float4*)G;
#pragma unroll
        for (int ql = 0; ql < 8; ++ql) {
            const int q = qh * 8 + ql;
            float4 acc = {0.f, 0.f, 0.f, 0.f};
#pragma unroll
            for (int r = 0; r < 8; ++r) {
                float4 g = G4[ql * 256 + r * 32 + j * 2 + kq];
                acc.x += a[r] * g.x; acc.y += a[r] * g.y;
                acc.z += a[r] * g.z; acc.w += a[r] * g.w;
            }
            f16x4 h4;
            h4[0] = (_Float16)acc.x; h4[1] = (_Float16)acc.y;
            h4[2] = (_Float16)acc.z; h4[3] = (_Float16)acc.w;
            *(f16x4*)(W0t + (size_t)((o * 16 + p) * 16 + q) * 1024 + t * 4) = h4;
        }
    } else {
        const int idx = b - 1536;
        const int o = idx >> 5, p = (idx >> 1) & 15, qh = idx & 1;
        // phase1: G[ql4][rj128][k16] = sum_ss c1b[rj,p,ss]*c1c[ss,k,q], q=qh*4+ql
        {
            const int h = t >> 6, pair = t & 63, ql = pair >> 4, k = pair & 15;
            const int q = qh * 4 + ql;
            float cr[8];
#pragma unroll
            for (int ss = 0; ss < 8; ++ss) cr[ss] = c1c[(ss * 16 + k) * 8 + q];
            for (int rj = h * 32; rj < h * 32 + 32; ++rj) {
                const float4* b4 = (const float4*)(c1b + (rj * 16 + p) * 8);
                float4 b0 = b4[0], b1 = b4[1];
                float s = b0.x * cr[0] + b0.y * cr[1] + b0.z * cr[2] + b0.w * cr[3]
                        + b1.x * cr[4] + b1.y * cr[5] + b1.z * cr[6] + b1.w * cr[7];
                G[ql * 2048 + rj * 16 + k] = s;
            }
        }
        __syncthreads();
        // phase2: W1t row (o*16+p)*8+q, q = qh*4+ql
        const int ig = t >> 6, j = (t >> 2) & 15, kq = t & 3;
        float a[4][8];
#pragma unroll
        for (int ii = 0; ii < 4; ++ii)
#pragma unroll
            for (int r = 0; r < 8; ++r) a[ii][r] = c1a[((ig * 4 + ii) * 8 + o) * 8 + r];
        const float4* G4 = (const float4*)G;
#pragma unroll
        for (int ql = 0; ql < 4; ++ql) {
            const int q = qh * 4 + ql;
            float4 acc[4] = {{0,0,0,0},{0,0,0,0},{0,0,0,0},{0,0,0,0}};
#pragma unroll
            for (int r = 0; r < 8; ++r) {
                float4 g = G4[ql * 512 + r * 64 + j * 4 + kq];
#pragma unroll
                for (int ii = 0; ii < 4; ++ii) {
                    acc[ii].x += a[ii][r] * g.x; acc[ii].y += a[ii][r] * g.y;
                    acc[ii].z += a[ii][r] * g.z; acc[ii].w += a[ii][r] * g.w;
                }
            }
            const size_t rowbase = (size_t)((o * 16 + p) * 8 + q) * 4096;
#pragma unroll
            for (int ii = 0; ii < 4; ++ii) {
                f16x4 h4;
                h4[0] = (_Float16)acc[ii].x; h4[1] = (_Float16)acc[ii].y;
                h4[2] = (_Float16)acc[ii].z; h4[3] = (_Float16)acc[ii].w;
                *(f16x4*)(W1t + rowbase + (ig * 4 + ii) * 256 + j * 16 + kq * 4) = h4;
            }
        }
    }
}

// -------- CHAMPION GEMM (R0/R9-verified, G1 = 93-95us measured): 128x128, BK=64,
// 32x32x16, XOR-swizzled row-major LDS, classic 2-barrier, 32KB LDS -> 5 blk/CU --------
template <int OUTMODE>
__global__ __launch_bounds__(256) void gemm32_kernel(
    const _Float16* __restrict__ A, const _Float16* __restrict__ Bt,
    const float* __restrict__ bias, void* __restrict__ Cout,
    int M, int N, int K) {
    constexpr int BK = 64;
    __shared__ alignas(16) _Float16 sA[128 * BK];
    __shared__ alignas(16) _Float16 sB[128 * BK];

    const int t = threadIdx.x, lane = t & 63, w = t >> 6;
    const int m0 = blockIdx.x * 128, n0 = blockIdx.y * 128;
    const int wm = (w & 1) * 64, wn = (w >> 1) * 64;
    const int l31 = lane & 31, lh = lane >> 5;

    f32x16 acc[2][2] = {};

    const int s0 = w * 256 + lane;
    const int row0 = s0 >> 3;
    const int cslot = s0 & 7;
    const int kofs = (cslot ^ (row0 & 7)) * 8;
    const _Float16* gA = A + (size_t)(m0 + row0) * K + kofs;
    const _Float16* gB = Bt + (size_t)(n0 + row0) * K + kofs;
    _Float16* lA = sA + s0 * 8;
    _Float16* lB = sB + s0 * 8;
    const size_t rs = (size_t)8 * K;

    for (int k0 = 0; k0 < K; k0 += BK) {
#pragma unroll
        for (int m = 0; m < 4; ++m) {
            async_copy16(gA + k0 + m * rs, lA + m * 512);
            async_copy16(gB + k0 + m * rs, lB + m * 512);
        }
        __syncthreads();
#pragma unroll
        for (int kk = 0; kk < 4; ++kk) {
            f16x8 af[2], bf[2];
            const int c = kk * 2 + lh;
            const int sl = (c ^ (l31 & 7)) * 8;
#pragma unroll
            for (int i = 0; i < 2; ++i) {
                af[i] = *(const f16x8*)(sA + (wm + i * 32 + l31) * BK + sl);
                bf[i] = *(const f16x8*)(sB + (wn + i * 32 + l31) * BK + sl);
            }
#pragma unroll
            for (int i = 0; i < 2; ++i)
#pragma unroll
                for (int j = 0; j < 2; ++j)
                    acc[i][j] = __builtin_amdgcn_mfma_f32_32x32x16_f16(af[i], bf[j], acc[i][j], 0, 0, 0);
        }
        __syncthreads();
    }

#pragma unroll
    for (int i = 0; i < 2; ++i)
#pragma unroll
        for (int j = 0; j < 2; ++j) {
            const int col = n0 + wn + j * 32 + l31;
            const float bv = bias[col];
            const int rbase = m0 + wm + i * 32 + 4 * lh;
            if (OUTMODE == 1) {
                _Float16* C = (_Float16*)Cout;
#pragma unroll
                for (int r = 0; r < 16; ++r) {
                    int row = rbase + (r & 3) + 8 * (r >> 2);
                    float v = acc[i][j][r] + bv;
                    float uu = v * (0.7978845608028654f + 0.0356774081363001f * v * v);
                    float e = __builtin_amdgcn_exp2f(uu * 2.8853900817779268f);
                    float rc = __builtin_amdgcn_rcpf(e + 1.0f);
                    C[(size_t)row * N + col] = (_Float16)(v * (1.0f - rc));
                }
            } else {
                float* C = (float*)Cout;
#pragma unroll
                for (int r = 0; r < 16; ++r) {
                    int row = rbase + (r & 3) + 8 * (r >> 2);
                    C[(size_t)row * N + col] = acc[i][j][r] + bv;
                }
            }
        }
}

// -------- Split-K x2 champion with fused atomic epilogue (no p1, no reduce pass) --------
// out pre-zeroed by our own hipMemsetAsync. z in {0,1} covers K-half; both halves
// unsafeAtomicAdd (native global_atomic_add_f32, L2-side RMW) their fp32 partial;
// z=0 folds in the bias. 1024 blocks -> 4 blk/CU (R9: splitk ~92us measured-by-ledger).
__global__ __launch_bounds__(256) void gemm32_splitk_atomic(
    const _Float16* __restrict__ A, const _Float16* __restrict__ Bt,
    const float* __restrict__ bias, float* __restrict__ out,
    int M, int N, int K) {
    constexpr int BK = 64;
    __shared__ alignas(16) _Float16 sA[128 * BK];
    __shared__ alignas(16) _Float16 sB[128 * BK];

    const int t = threadIdx.x, lane = t & 63, w = t >> 6;
    const int m0 = blockIdx.x * 128, n0 = blockIdx.y * 128;
    const int wm = (w & 1) * 64, wn = (w >> 1) * 64;
    const int l31 = lane & 31, lh = lane >> 5;

    f32x16 acc[2][2] = {};

    const int s0 = w * 256 + lane;
    const int row0 = s0 >> 3;
    const int cslot = s0 & 7;
    const int kofs = (cslot ^ (row0 & 7)) * 8;
    const _Float16* gA = A + (size_t)(m0 + row0) * K + kofs;
    const _Float16* gB = Bt + (size_t)(n0 + row0) * K + kofs;
    _Float16* lA = sA + s0 * 8;
    _Float16* lB = sB + s0 * 8;
    const size_t rs = (size_t)8 * K;

    const int kbase = blockIdx.z * (K >> 1);
    const int kend = kbase + (K >> 1);
    for (int k0 = kbase; k0 < kend; k0 += BK) {
#pragma unroll
        for (int m = 0; m < 4; ++m) {
            async_copy16(gA + k0 + m * rs, lA + m * 512);
            async_copy16(gB + k0 + m * rs, lB + m * 512);
        }
        __syncthreads();
#pragma unroll
        for (int kk = 0; kk < 4; ++kk) {
            f16x8 af[2], bf[2];
            const int c = kk * 2 + lh;
            const int sl = (c ^ (l31 & 7)) * 8;
#pragma unroll
            for (int i = 0; i < 2; ++i) {
                af[i] = *(const f16x8*)(sA + (wm + i * 32 + l31) * BK + sl);
                bf[i] = *(const f16x8*)(sB + (wn + i * 32 + l31) * BK + sl);
            }
#pragma unroll
            for (int i = 0; i < 2; ++i)
#pragma unroll
                for (int j = 0; j < 2; ++j)
                    acc[i][j] = __builtin_amdgcn_mfma_f32_32x32x16_f16(af[i], bf[j], acc[i][j], 0, 0, 0);
        }
        __syncthreads();
    }

#pragma unroll
    for (int i = 0; i < 2; ++i)
#pragma unroll
        for (int j = 0; j < 2; ++j) {
            const int col = n0 + wn + j * 32 + l31;
            const float bv = (blockIdx.z == 0) ? bias[col] : 0.f;
            const int rbase = m0 + wm + i * 32 + 4 * lh;
#pragma unroll
            for (int r = 0; r < 16; ++r) {
                int row = rbase + (r & 3) + 8 * (r >> 2);
                unsafeAtomicAdd(&out[(size_t)row * N + col], acc[i][j][r] + bv);
            }
        }
}

extern "C" void kernel_launch(void* const* d_in, const int* in_sizes, int n_in,
                              void* d_out, int out_size, void* d_ws, size_t ws_size,
                              hipStream_t stream) {
    const float* x   = (const float*)d_in[0];
    const float* c0a = (const float*)d_in[1];
    const float* c0b = (const float*)d_in[2];
    const float* c0c = (const float*)d_in[3];
    const float* b0  = (const float*)d_in[4];
    const float* c1a = (const float*)d_in[5];
    const float* c1b = (const float*)d_in[6];
    const float* c1c = (const float*)d_in[7];
    const float* b1  = (const float*)d_in[8];
    float* out = (float*)d_out;

    char* ws = (char*)d_ws;
    _Float16* xh  = (_Float16*)(ws);                          // 16 MB
    _Float16* W0t = (_Float16*)(ws + (size_t)(16u << 20));    //  8 MB
    _Float16* W1t = (_Float16*)(ws + (size_t)(24u << 20));    //  8 MB
    _Float16* h   = (_Float16*)(ws + (size_t)(32u << 20));    // 64 MB

    // 0) zero out for the atomic split-K epilogue (graph-capturable stream op)
    hipMemsetAsync(out, 0, (size_t)8192 * 1024 * sizeof(float), stream);
    // 1) fused prep (32KB LDS): cast + W0 halves + W1 halves (1792 blocks)
    prep_kernel<<<dim3(1792), dim3(256), 0, stream>>>(
        x, xh, c0a, c0b, c0c, W0t, c1a, c1b, c1c, W1t);
    // 2) h = gelu(x @ W0 + b0)   M=8192 N=4096 K=1024  (champion, 2048 blocks)
    gemm32_kernel<1><<<dim3(64, 32), dim3(256), 0, stream>>>(
        xh, W0t, b0, (void*)h, 8192, 4096, 1024);
    // 3) out += h @ W1 (+b1 on z=0)  M=8192 N=1024 K=4096  (split-K x2, atomic)
    gemm32_splitk_atomic<<<dim3(64, 8, 2), dim3(256), 0, stream>>>(
        h, W1t, b1, out, 8192, 1024, 4096);
}

// Round 11
// 265.678 us; speedup vs baseline: 1.1839x; 1.1839x over previous
//
#include <hip/hip_runtime.h>
#include <math.h>

typedef _Float16 f16x8 __attribute__((ext_vector_type(8)));
typedef _Float16 f16x4 __attribute__((ext_vector_type(4)));
typedef float f32x16 __attribute__((ext_vector_type(16)));

__device__ __forceinline__ void async_copy16(const void* g, void* l) {
    __builtin_amdgcn_global_load_lds(
        (const __attribute__((address_space(1))) void*)g,
        (__attribute__((address_space(3))) void*)l, 16, 0, 0);
}

// ---------------- cast x -> f16 (split out of prep for attribution) ----------------
__global__ __launch_bounds__(256) void cast_kernel(
    const float* __restrict__ x, _Float16* __restrict__ xh) {
    const float4* in4 = (const float4*)x;
    f16x4* out4 = (f16x4*)xh;
    const int base = blockIdx.x * 2048 + threadIdx.x;
#pragma unroll
    for (int u = 0; u < 8; ++u) {
        float4 v = in4[base + u * 256];
        f16x4 o;
        o[0] = (_Float16)v.x; o[1] = (_Float16)v.y;
        o[2] = (_Float16)v.z; o[3] = (_Float16)v.w;
        out4[base + u * 256] = o;
    }
}

// ---------------- weight build (R6-verified restructured G-build, 64KB G) ----------------
// blocks 0..255  : W0t, (o,p) = idx{>>4, &15}
// blocks 256..383: W1t, (o,p) = idx{>>4, &15}
__global__ __launch_bounds__(256) void weight_kernel(
    const float* __restrict__ c0a, const float* __restrict__ c0b,
    const float* __restrict__ c0c, _Float16* __restrict__ W0t,
    const float* __restrict__ c1a, const float* __restrict__ c1b,
    const float* __restrict__ c1c, _Float16* __restrict__ W1t) {
    __shared__ float G[16384];
    const int b = blockIdx.x, t = threadIdx.x;
    if (b < 256) {
        const int o = b >> 4, p = b & 15;
        // G[q16][rj128][k8] = sum_ss c0b[rj,p,ss]*c0c[ss,k,q]
        {
            const int h = t >> 7, qk = t & 127, q = qk >> 3, k = qk & 7;
            float cr[8];
#pragma unroll
            for (int ss = 0; ss < 8; ++ss) cr[ss] = c0c[(ss * 8 + k) * 16 + q];
            for (int rj = h * 64; rj < h * 64 + 64; ++rj) {
                const float4* b4 = (const float4*)(c0b + (rj * 16 + p) * 8);
                float4 b0 = b4[0], b1 = b4[1];
                float s = b0.x * cr[0] + b0.y * cr[1] + b0.z * cr[2] + b0.w * cr[3]
                        + b1.x * cr[4] + b1.y * cr[5] + b1.z * cr[6] + b1.w * cr[7];
                G[q * 1024 + rj * 8 + k] = s;
            }
        }
        __syncthreads();
        const int i = t >> 5, j = (t >> 1) & 15, kq = t & 1;
        float a[8];
#pragma unroll
        for (int r = 0; r < 8; ++r) a[r] = c0a[(i * 16 + o) * 8 + r];
        const float4* G4 = (const float4*)G;
#pragma unroll
        for (int q = 0; q < 16; ++q) {
            float4 acc = {0.f, 0.f, 0.f, 0.f};
#pragma unroll
            for (int r = 0; r < 8; ++r) {
                float4 g = G4[q * 256 + r * 32 + j * 2 + kq];
                acc.x += a[r] * g.x; acc.y += a[r] * g.y;
                acc.z += a[r] * g.z; acc.w += a[r] * g.w;
            }
            f16x4 h4;
            h4[0] = (_Float16)acc.x; h4[1] = (_Float16)acc.y;
            h4[2] = (_Float16)acc.z; h4[3] = (_Float16)acc.w;
            *(f16x4*)(W0t + (size_t)((o * 16 + p) * 16 + q) * 1024 + t * 4) = h4;
        }
    } else {
        const int idx = b - 256;
        const int o = idx >> 4, p = idx & 15;
        // G[q8][rj128][k16] = sum_ss c1b[rj,p,ss]*c1c[ss,k,q]
        {
            const int h = t >> 7, qk = t & 127, q = qk >> 4, k = qk & 15;
            float cr[8];
#pragma unroll
            for (int ss = 0; ss < 8; ++ss) cr[ss] = c1c[(ss * 16 + k) * 8 + q];
            for (int rj = h * 64; rj < h * 64 + 64; ++rj) {
                const float4* b4 = (const float4*)(c1b + (rj * 16 + p) * 8);
                float4 b0 = b4[0], b1 = b4[1];
                float s = b0.x * cr[0] + b0.y * cr[1] + b0.z * cr[2] + b0.w * cr[3]
                        + b1.x * cr[4] + b1.y * cr[5] + b1.z * cr[6] + b1.w * cr[7];
                G[q * 2048 + rj * 16 + k] = s;
            }
        }
        __syncthreads();
        const int ig = t >> 6, j = (t >> 2) & 15, kq = t & 3;
        float a[4][8];
#pragma unroll
        for (int ii = 0; ii < 4; ++ii)
#pragma unroll
            for (int r = 0; r < 8; ++r) a[ii][r] = c1a[((ig * 4 + ii) * 8 + o) * 8 + r];
        const float4* G4 = (const float4*)G;
#pragma unroll
        for (int q = 0; q < 8; ++q) {
            float4 acc[4] = {{0,0,0,0},{0,0,0,0},{0,0,0,0},{0,0,0,0}};
#pragma unroll
            for (int r = 0; r < 8; ++r) {
                float4 g = G4[q * 512 + r * 64 + j * 4 + kq];
#pragma unroll
                for (int ii = 0; ii < 4; ++ii) {
                    acc[ii].x += a[ii][r] * g.x; acc[ii].y += a[ii][r] * g.y;
                    acc[ii].z += a[ii][r] * g.z; acc[ii].w += a[ii][r] * g.w;
                }
            }
            const size_t rowbase = (size_t)((o * 16 + p) * 8 + q) * 4096;
#pragma unroll
            for (int ii = 0; ii < 4; ++ii) {
                f16x4 h4;
                h4[0] = (_Float16)acc[ii].x; h4[1] = (_Float16)acc[ii].y;
                h4[2] = (_Float16)acc[ii].z; h4[3] = (_Float16)acc[ii].w;
                *(f16x4*)(W1t + rowbase + (ig * 4 + ii) * 256 + j * 16 + kq * 4) = h4;
            }
        }
    }
}

// -------- CHAMPION GEMM (R0/R9-verified, G1 = 93-95us measured): 128x128, BK=64,
// 32x32x16, XOR-swizzled row-major LDS, classic 2-barrier, 32KB LDS -> 5 blk/CU --------
template <int OUTMODE>
__global__ __launch_bounds__(256) void gemm32_kernel(
    const _Float16* __restrict__ A, const _Float16* __restrict__ Bt,
    const float* __restrict__ bias, void* __restrict__ Cout,
    int M, int N, int K) {
    constexpr int BK = 64;
    __shared__ alignas(16) _Float16 sA[128 * BK];
    __shared__ alignas(16) _Float16 sB[128 * BK];

    const int t = threadIdx.x, lane = t & 63, w = t >> 6;
    const int m0 = blockIdx.x * 128, n0 = blockIdx.y * 128;
    const int wm = (w & 1) * 64, wn = (w >> 1) * 64;
    const int l31 = lane & 31, lh = lane >> 5;

    f32x16 acc[2][2] = {};

    const int s0 = w * 256 + lane;
    const int row0 = s0 >> 3;
    const int cslot = s0 & 7;
    const int kofs = (cslot ^ (row0 & 7)) * 8;
    const _Float16* gA = A + (size_t)(m0 + row0) * K + kofs;
    const _Float16* gB = Bt + (size_t)(n0 + row0) * K + kofs;
    _Float16* lA = sA + s0 * 8;
    _Float16* lB = sB + s0 * 8;
    const size_t rs = (size_t)8 * K;

    for (int k0 = 0; k0 < K; k0 += BK) {
#pragma unroll
        for (int m = 0; m < 4; ++m) {
            async_copy16(gA + k0 + m * rs, lA + m * 512);
            async_copy16(gB + k0 + m * rs, lB + m * 512);
        }
        __syncthreads();
#pragma unroll
        for (int kk = 0; kk < 4; ++kk) {
            f16x8 af[2], bf[2];
            const int c = kk * 2 + lh;
            const int sl = (c ^ (l31 & 7)) * 8;
#pragma unroll
            for (int i = 0; i < 2; ++i) {
                af[i] = *(const f16x8*)(sA + (wm + i * 32 + l31) * BK + sl);
                bf[i] = *(const f16x8*)(sB + (wn + i * 32 + l31) * BK + sl);
            }
#pragma unroll
            for (int i = 0; i < 2; ++i)
#pragma unroll
                for (int j = 0; j < 2; ++j)
                    acc[i][j] = __builtin_amdgcn_mfma_f32_32x32x16_f16(af[i], bf[j], acc[i][j], 0, 0, 0);
        }
        __syncthreads();
    }

#pragma unroll
    for (int i = 0; i < 2; ++i)
#pragma unroll
        for (int j = 0; j < 2; ++j) {
            const int col = n0 + wn + j * 32 + l31;
            const float bv = bias[col];
            const int rbase = m0 + wm + i * 32 + 4 * lh;
            if (OUTMODE == 1) {
                _Float16* C = (_Float16*)Cout;
#pragma unroll
                for (int r = 0; r < 16; ++r) {
                    int row = rbase + (r & 3) + 8 * (r >> 2);
                    float v = acc[i][j][r] + bv;
                    float uu = v * (0.7978845608028654f + 0.0356774081363001f * v * v);
                    float e = __builtin_amdgcn_exp2f(uu * 2.8853900817779268f);
                    float rc = __builtin_amdgcn_rcpf(e + 1.0f);
                    C[(size_t)row * N + col] = (_Float16)(v * (1.0f - rc));
                }
            } else {
                float* C = (float*)Cout;
#pragma unroll
                for (int r = 0; r < 16; ++r) {
                    int row = rbase + (r & 3) + 8 * (r >> 2);
                    C[(size_t)row * N + col] = acc[i][j][r] + bv;
                }
            }
        }
}

// -------- In-block split-K champion (G2): 512 thr = 2 groups x 4 waves; group g
// runs the EXACT champion pipeline over K-half g with its own 32KB LDS half;
// shared __syncthreads keeps groups lockstepped (equal trip counts). After the
// K-loop the LDS is dead: group 1 parks its 64 accs/thread there (transposed
// xch[e*256+tl] -> bank tl%32, conflict-free), one barrier, group 0 adds
// partials + bias and does the single fp32 store. Kills R9's reduce pass
// (~22us) + 96MB partial traffic. 64KB LDS -> 2 blk/CU = 16 waves/CU (same
// TLP as R9's 4blk/CU x 4 waves splitk, measured ~93us). --------
__global__ __launch_bounds__(512) void gemm32_splitk_lds(
    const _Float16* __restrict__ A, const _Float16* __restrict__ Bt,
    const float* __restrict__ bias, float* __restrict__ out,
    int M, int N, int K) {
    constexpr int BK = 64;
    __shared__ alignas(16) _Float16 smem[32768];  // [g][A|B][8192] = 64KB

    const int t = threadIdx.x;
    const int g = t >> 8, tl = t & 255;
    const int lane = tl & 63, wg = tl >> 6;
    const int m0 = blockIdx.x * 128, n0 = blockIdx.y * 128;
    const int wm = (wg & 1) * 64, wn = (wg >> 1) * 64;
    const int l31 = lane & 31, lh = lane >> 5;

    _Float16* sA = smem + g * 16384;
    _Float16* sB = sA + 8192;

    f32x16 acc[2][2] = {};

    const int s0 = wg * 256 + lane;
    const int row0 = s0 >> 3;
    const int cslot = s0 & 7;
    const int kofs = (cslot ^ (row0 & 7)) * 8;
    const _Float16* gA = A + (size_t)(m0 + row0) * K + kofs;
    const _Float16* gB = Bt + (size_t)(n0 + row0) * K + kofs;
    _Float16* lA = sA + s0 * 8;
    _Float16* lB = sB + s0 * 8;
    const size_t rs = (size_t)8 * K;

    const int kbase = g * (K >> 1);
    const int kend = kbase + (K >> 1);
    for (int k0 = kbase; k0 < kend; k0 += BK) {
#pragma unroll
        for (int m = 0; m < 4; ++m) {
            async_copy16(gA + k0 + m * rs, lA + m * 512);
            async_copy16(gB + k0 + m * rs, lB + m * 512);
        }
        __syncthreads();
#pragma unroll
        for (int kk = 0; kk < 4; ++kk) {
            f16x8 af[2], bf[2];
            const int c = kk * 2 + lh;
            const int sl = (c ^ (l31 & 7)) * 8;
#pragma unroll
            for (int i = 0; i < 2; ++i) {
                af[i] = *(const f16x8*)(sA + (wm + i * 32 + l31) * BK + sl);
                bf[i] = *(const f16x8*)(sB + (wn + i * 32 + l31) * BK + sl);
            }
#pragma unroll
            for (int i = 0; i < 2; ++i)
#pragma unroll
                for (int j = 0; j < 2; ++j)
                    acc[i][j] = __builtin_amdgcn_mfma_f32_32x32x16_f16(af[i], bf[j], acc[i][j], 0, 0, 0);
        }
        __syncthreads();   // final iter: also publishes "LDS reads done" for xch reuse
    }

    // ---- combine: group1 -> xch (LDS), group0 adds + bias + single store ----
    float* xch = (float*)smem;  // 16384 floats = 64KB, exactly 256 thr x 64 accs
    if (g == 1) {
#pragma unroll
        for (int i = 0; i < 2; ++i)
#pragma unroll
            for (int j = 0; j < 2; ++j)
#pragma unroll
                for (int r = 0; r < 16; ++r)
                    xch[((i * 2 + j) * 16 + r) * 256 + tl] = acc[i][j][r];
    }
    __syncthreads();
    if (g == 0) {
#pragma unroll
        for (int i = 0; i < 2; ++i)
#pragma unroll
            for (int j = 0; j < 2; ++j) {
                const int col = n0 + wn + j * 32 + l31;
                const float bv = bias[col];
                const int rbase = m0 + wm + i * 32 + 4 * lh;
#pragma unroll
                for (int r = 0; r < 16; ++r) {
                    int row = rbase + (r & 3) + 8 * (r >> 2);
                    float v = acc[i][j][r] + xch[((i * 2 + j) * 16 + r) * 256 + tl] + bv;
                    out[(size_t)row * N + col] = v;
                }
            }
    }
}

extern "C" void kernel_launch(void* const* d_in, const int* in_sizes, int n_in,
                              void* d_out, int out_size, void* d_ws, size_t ws_size,
                              hipStream_t stream) {
    const float* x   = (const float*)d_in[0];
    const float* c0a = (const float*)d_in[1];
    const float* c0b = (const float*)d_in[2];
    const float* c0c = (const float*)d_in[3];
    const float* b0  = (const float*)d_in[4];
    const float* c1a = (const float*)d_in[5];
    const float* c1b = (const float*)d_in[6];
    const float* c1c = (const float*)d_in[7];
    const float* b1  = (const float*)d_in[8];
    float* out = (float*)d_out;

    char* ws = (char*)d_ws;
    _Float16* xh  = (_Float16*)(ws);                          // 16 MB
    _Float16* W0t = (_Float16*)(ws + (size_t)(16u << 20));    //  8 MB
    _Float16* W1t = (_Float16*)(ws + (size_t)(24u << 20));    //  8 MB
    _Float16* h   = (_Float16*)(ws + (size_t)(32u << 20));    // 64 MB

    // 1a) cast x -> f16 (1024 blocks)   [split from prep for attribution]
    cast_kernel<<<dim3(1024), dim3(256), 0, stream>>>(x, xh);
    // 1b) weight builds (384 blocks)
    weight_kernel<<<dim3(384), dim3(256), 0, stream>>>(
        c0a, c0b, c0c, W0t, c1a, c1b, c1c, W1t);
    // 2) h = gelu(x @ W0 + b0)   M=8192 N=4096 K=1024  (champion, 2048 blocks)
    gemm32_kernel<1><<<dim3(64, 32), dim3(256), 0, stream>>>(
        xh, W0t, b0, (void*)h, 8192, 4096, 1024);
    // 3) out = h @ W1 + b1       M=8192 N=1024 K=4096  (in-block split-K, 512 blocks)
    gemm32_splitk_lds<<<dim3(64, 8), dim3(512), 0, stream>>>(
        h, W1t, b1, out, 8192, 1024, 4096);
}

// Round 12
// 260.391 us; speedup vs baseline: 1.2080x; 1.0203x over previous
//
#include <hip/hip_runtime.h>
#include <math.h>

typedef _Float16 f16x8 __attribute__((ext_vector_type(8)));
typedef _Float16 f16x4 __attribute__((ext_vector_type(4)));
typedef float f32x16 __attribute__((ext_vector_type(16)));

__device__ __forceinline__ void async_copy16(const void* g, void* l) {
    __builtin_amdgcn_global_load_lds(
        (const __attribute__((address_space(1))) void*)g,
        (__attribute__((address_space(3))) void*)l, 16, 0, 0);
}

// ---------------- fused prep, WEIGHT-FIRST ordering ----------------
// blocks 0..255   : W0t build (o,p) = b{>>4,&15}     [long latency chains]
// blocks 256..383 : W1t build (idx = b-256)           [long latency chains]
// blocks 384..1407: cast x->f16 (cb = b-384)          [pure BW]
// Rationale: weight blocks dispatch FIRST so their serial-load chains run
// concurrently with the cast's BW phase instead of as a post-drain tail.
__global__ __launch_bounds__(256) void prep_kernel(
    const float* __restrict__ x, _Float16* __restrict__ xh,
    const float* __restrict__ c0a, const float* __restrict__ c0b,
    const float* __restrict__ c0c, _Float16* __restrict__ W0t,
    const float* __restrict__ c1a, const float* __restrict__ c1b,
    const float* __restrict__ c1c, _Float16* __restrict__ W1t) {
    __shared__ float G[16384];
    const int b = blockIdx.x, t = threadIdx.x;
    if (b >= 384) {
        const float4* in4 = (const float4*)x;
        f16x4* out4 = (f16x4*)xh;
        const int base = (b - 384) * 2048 + t;
#pragma unroll
        for (int u = 0; u < 8; ++u) {
            float4 v = in4[base + u * 256];
            f16x4 o;
            o[0] = (_Float16)v.x; o[1] = (_Float16)v.y;
            o[2] = (_Float16)v.z; o[3] = (_Float16)v.w;
            out4[base + u * 256] = o;
        }
    } else if (b < 256) {
        const int o = b >> 4, p = b & 15;
        // G[q16][rj128][k8] = sum_ss c0b[rj,p,ss]*c0c[ss,k,q]
        {
            const int h = t >> 7, qk = t & 127, q = qk >> 3, k = qk & 7;
            float cr[8];
#pragma unroll
            for (int ss = 0; ss < 8; ++ss) cr[ss] = c0c[(ss * 8 + k) * 16 + q];
            for (int rj = h * 64; rj < h * 64 + 64; ++rj) {
                const float4* b4 = (const float4*)(c0b + (rj * 16 + p) * 8);
                float4 b0 = b4[0], b1 = b4[1];
                float s = b0.x * cr[0] + b0.y * cr[1] + b0.z * cr[2] + b0.w * cr[3]
                        + b1.x * cr[4] + b1.y * cr[5] + b1.z * cr[6] + b1.w * cr[7];
                G[q * 1024 + rj * 8 + k] = s;
            }
        }
        __syncthreads();
        const int i = t >> 5, j = (t >> 1) & 15, kq = t & 1;
        float a[8];
#pragma unroll
        for (int r = 0; r < 8; ++r) a[r] = c0a[(i * 16 + o) * 8 + r];
        const float4* G4 = (const float4*)G;
#pragma unroll
        for (int q = 0; q < 16; ++q) {
            float4 acc = {0.f, 0.f, 0.f, 0.f};
#pragma unroll
            for (int r = 0; r < 8; ++r) {
                float4 g = G4[q * 256 + r * 32 + j * 2 + kq];
                acc.x += a[r] * g.x; acc.y += a[r] * g.y;
                acc.z += a[r] * g.z; acc.w += a[r] * g.w;
            }
            f16x4 h4;
            h4[0] = (_Float16)acc.x; h4[1] = (_Float16)acc.y;
            h4[2] = (_Float16)acc.z; h4[3] = (_Float16)acc.w;
            *(f16x4*)(W0t + (size_t)((o * 16 + p) * 16 + q) * 1024 + t * 4) = h4;
        }
    } else {
        const int idx = b - 256;
        const int o = idx >> 4, p = idx & 15;
        // G[q8][rj128][k16] = sum_ss c1b[rj,p,ss]*c1c[ss,k,q]
        {
            const int h = t >> 7, qk = t & 127, q = qk >> 4, k = qk & 15;
            float cr[8];
#pragma unroll
            for (int ss = 0; ss < 8; ++ss) cr[ss] = c1c[(ss * 16 + k) * 8 + q];
            for (int rj = h * 64; rj < h * 64 + 64; ++rj) {
                const float4* b4 = (const float4*)(c1b + (rj * 16 + p) * 8);
                float4 b0 = b4[0], b1 = b4[1];
                float s = b0.x * cr[0] + b0.y * cr[1] + b0.z * cr[2] + b0.w * cr[3]
                        + b1.x * cr[4] + b1.y * cr[5] + b1.z * cr[6] + b1.w * cr[7];
                G[q * 2048 + rj * 16 + k] = s;
            }
        }
        __syncthreads();
        const int ig = t >> 6, j = (t >> 2) & 15, kq = t & 3;
        float a[4][8];
#pragma unroll
        for (int ii = 0; ii < 4; ++ii)
#pragma unroll
            for (int r = 0; r < 8; ++r) a[ii][r] = c1a[((ig * 4 + ii) * 8 + o) * 8 + r];
        const float4* G4 = (const float4*)G;
#pragma unroll
        for (int q = 0; q < 8; ++q) {
            float4 acc[4] = {{0,0,0,0},{0,0,0,0},{0,0,0,0},{0,0,0,0}};
#pragma unroll
            for (int r = 0; r < 8; ++r) {
                float4 g = G4[q * 512 + r * 64 + j * 4 + kq];
#pragma unroll
                for (int ii = 0; ii < 4; ++ii) {
                    acc[ii].x += a[ii][r] * g.x; acc[ii].y += a[ii][r] * g.y;
                    acc[ii].z += a[ii][r] * g.z; acc[ii].w += a[ii][r] * g.w;
                }
            }
            const size_t rowbase = (size_t)((o * 16 + p) * 8 + q) * 4096;
#pragma unroll
            for (int ii = 0; ii < 4; ++ii) {
                f16x4 h4;
                h4[0] = (_Float16)acc[ii].x; h4[1] = (_Float16)acc[ii].y;
                h4[2] = (_Float16)acc[ii].z; h4[3] = (_Float16)acc[ii].w;
                *(f16x4*)(W1t + rowbase + (ig * 4 + ii) * 256 + j * 16 + kq * 4) = h4;
            }
        }
    }
}

// -------- CHAMPION GEMM (R0/R9/R11-verified, G1 = 93-95us): 128x128, BK=64,
// 32x32x16, XOR-swizzled row-major LDS, classic 2-barrier, 32KB LDS -> 5 blk/CU --------
template <int OUTMODE>
__global__ __launch_bounds__(256) void gemm32_kernel(
    const _Float16* __restrict__ A, const _Float16* __restrict__ Bt,
    const float* __restrict__ bias, void* __restrict__ Cout,
    int M, int N, int K) {
    constexpr int BK = 64;
    __shared__ alignas(16) _Float16 sA[128 * BK];
    __shared__ alignas(16) _Float16 sB[128 * BK];

    const int t = threadIdx.x, lane = t & 63, w = t >> 6;
    const int m0 = blockIdx.x * 128, n0 = blockIdx.y * 128;
    const int wm = (w & 1) * 64, wn = (w >> 1) * 64;
    const int l31 = lane & 31, lh = lane >> 5;

    f32x16 acc[2][2] = {};

    const int s0 = w * 256 + lane;
    const int row0 = s0 >> 3;
    const int cslot = s0 & 7;
    const int kofs = (cslot ^ (row0 & 7)) * 8;
    const _Float16* gA = A + (size_t)(m0 + row0) * K + kofs;
    const _Float16* gB = Bt + (size_t)(n0 + row0) * K + kofs;
    _Float16* lA = sA + s0 * 8;
    _Float16* lB = sB + s0 * 8;
    const size_t rs = (size_t)8 * K;

    for (int k0 = 0; k0 < K; k0 += BK) {
#pragma unroll
        for (int m = 0; m < 4; ++m) {
            async_copy16(gA + k0 + m * rs, lA + m * 512);
            async_copy16(gB + k0 + m * rs, lB + m * 512);
        }
        __syncthreads();
#pragma unroll
        for (int kk = 0; kk < 4; ++kk) {
            f16x8 af[2], bf[2];
            const int c = kk * 2 + lh;
            const int sl = (c ^ (l31 & 7)) * 8;
#pragma unroll
            for (int i = 0; i < 2; ++i) {
                af[i] = *(const f16x8*)(sA + (wm + i * 32 + l31) * BK + sl);
                bf[i] = *(const f16x8*)(sB + (wn + i * 32 + l31) * BK + sl);
            }
#pragma unroll
            for (int i = 0; i < 2; ++i)
#pragma unroll
                for (int j = 0; j < 2; ++j)
                    acc[i][j] = __builtin_amdgcn_mfma_f32_32x32x16_f16(af[i], bf[j], acc[i][j], 0, 0, 0);
        }
        __syncthreads();
    }

#pragma unroll
    for (int i = 0; i < 2; ++i)
#pragma unroll
        for (int j = 0; j < 2; ++j) {
            const int col = n0 + wn + j * 32 + l31;
            const float bv = bias[col];
            const int rbase = m0 + wm + i * 32 + 4 * lh;
            if (OUTMODE == 1) {
                _Float16* C = (_Float16*)Cout;
#pragma unroll
                for (int r = 0; r < 16; ++r) {
                    int row = rbase + (r & 3) + 8 * (r >> 2);
                    float v = acc[i][j][r] + bv;
                    float uu = v * (0.7978845608028654f + 0.0356774081363001f * v * v);
                    float e = __builtin_amdgcn_exp2f(uu * 2.8853900817779268f);
                    float rc = __builtin_amdgcn_rcpf(e + 1.0f);
                    C[(size_t)row * N + col] = (_Float16)(v * (1.0f - rc));
                }
            } else {
                float* C = (float*)Cout;
#pragma unroll
                for (int r = 0; r < 16; ++r) {
                    int row = rbase + (r & 3) + 8 * (r >> 2);
                    C[(size_t)row * N + col] = acc[i][j][r] + bv;
                }
            }
        }
}

// -------- In-block split-K champion (G2, R11-verified): 512 thr = 2 groups x 4 waves;
// group g runs the exact champion pipeline over K-half g in its own 32KB LDS half;
// after the K-loop group1 parks accs in dead LDS, group0 adds + bias + stores. --------
__global__ __launch_bounds__(512) void gemm32_splitk_lds(
    const _Float16* __restrict__ A, const _Float16* __restrict__ Bt,
    const float* __restrict__ bias, float* __restrict__ out,
    int M, int N, int K) {
    constexpr int BK = 64;
    __shared__ alignas(16) _Float16 smem[32768];  // [g][A|B][8192] = 64KB

    const int t = threadIdx.x;
    const int g = t >> 8, tl = t & 255;
    const int lane = tl & 63, wg = tl >> 6;
    const int m0 = blockIdx.x * 128, n0 = blockIdx.y * 128;
    const int wm = (wg & 1) * 64, wn = (wg >> 1) * 64;
    const int l31 = lane & 31, lh = lane >> 5;

    _Float16* sA = smem + g * 16384;
    _Float16* sB = sA + 8192;

    f32x16 acc[2][2] = {};

    const int s0 = wg * 256 + lane;
    const int row0 = s0 >> 3;
    const int cslot = s0 & 7;
    const int kofs = (cslot ^ (row0 & 7)) * 8;
    const _Float16* gA = A + (size_t)(m0 + row0) * K + kofs;
    const _Float16* gB = Bt + (size_t)(n0 + row0) * K + kofs;
    _Float16* lA = sA + s0 * 8;
    _Float16* lB = sB + s0 * 8;
    const size_t rs = (size_t)8 * K;

    const int kbase = g * (K >> 1);
    const int kend = kbase + (K >> 1);
    for (int k0 = kbase; k0 < kend; k0 += BK) {
#pragma unroll
        for (int m = 0; m < 4; ++m) {
            async_copy16(gA + k0 + m * rs, lA + m * 512);
            async_copy16(gB + k0 + m * rs, lB + m * 512);
        }
        __syncthreads();
#pragma unroll
        for (int kk = 0; kk < 4; ++kk) {
            f16x8 af[2], bf[2];
            const int c = kk * 2 + lh;
            const int sl = (c ^ (l31 & 7)) * 8;
#pragma unroll
            for (int i = 0; i < 2; ++i) {
                af[i] = *(const f16x8*)(sA + (wm + i * 32 + l31) * BK + sl);
                bf[i] = *(const f16x8*)(sB + (wn + i * 32 + l31) * BK + sl);
            }
#pragma unroll
            for (int i = 0; i < 2; ++i)
#pragma unroll
                for (int j = 0; j < 2; ++j)
                    acc[i][j] = __builtin_amdgcn_mfma_f32_32x32x16_f16(af[i], bf[j], acc[i][j], 0, 0, 0);
        }
        __syncthreads();
    }

    float* xch = (float*)smem;  // 16384 floats, exactly 256 thr x 64 accs
    if (g == 1) {
#pragma unroll
        for (int i = 0; i < 2; ++i)
#pragma unroll
            for (int j = 0; j < 2; ++j)
#pragma unroll
                for (int r = 0; r < 16; ++r)
                    xch[((i * 2 + j) * 16 + r) * 256 + tl] = acc[i][j][r];
    }
    __syncthreads();
    if (g == 0) {
#pragma unroll
        for (int i = 0; i < 2; ++i)
#pragma unroll
            for (int j = 0; j < 2; ++j) {
                const int col = n0 + wn + j * 32 + l31;
                const float bv = bias[col];
                const int rbase = m0 + wm + i * 32 + 4 * lh;
#pragma unroll
                for (int r = 0; r < 16; ++r) {
                    int row = rbase + (r & 3) + 8 * (r >> 2);
                    out[(size_t)row * N + col] =
                        acc[i][j][r] + xch[((i * 2 + j) * 16 + r) * 256 + tl] + bv;
                }
            }
    }
}

extern "C" void kernel_launch(void* const* d_in, const int* in_sizes, int n_in,
                              void* d_out, int out_size, void* d_ws, size_t ws_size,
                              hipStream_t stream) {
    const float* x   = (const float*)d_in[0];
    const float* c0a = (const float*)d_in[1];
    const float* c0b = (const float*)d_in[2];
    const float* c0c = (const float*)d_in[3];
    const float* b0  = (const float*)d_in[4];
    const float* c1a = (const float*)d_in[5];
    const float* c1b = (const float*)d_in[6];
    const float* c1c = (const float*)d_in[7];
    const float* b1  = (const float*)d_in[8];
    float* out = (float*)d_out;

    char* ws = (char*)d_ws;
    _Float16* xh  = (_Float16*)(ws);                          // 16 MB
    _Float16* W0t = (_Float16*)(ws + (size_t)(16u << 20));    //  8 MB
    _Float16* W1t = (_Float16*)(ws + (size_t)(24u << 20));    //  8 MB
    _Float16* h   = (_Float16*)(ws + (size_t)(32u << 20));    // 64 MB

    // 1) fused prep, weight-first block order (1408 blocks)
    prep_kernel<<<dim3(1408), dim3(256), 0, stream>>>(
        x, xh, c0a, c0b, c0c, W0t, c1a, c1b, c1c, W1t);
    // 2) h = gelu(x @ W0 + b0)   M=8192 N=4096 K=1024  (champion, 2048 blocks)
    gemm32_kernel<1><<<dim3(64, 32), dim3(256), 0, stream>>>(
        xh, W0t, b0, (void*)h, 8192, 4096, 1024);
    // 3) out = h @ W1 + b1       M=8192 N=1024 K=4096  (in-block split-K, 512 blocks)
    gemm32_splitk_lds<<<dim3(64, 8), dim3(512), 0, stream>>>(
        h, W1t, b1, out, 8192, 1024, 4096);
}